// Round 1
// baseline (217.064 us; speedup 1.0000x reference)
//
#include <hip/hip_runtime.h>
#include <math.h>

#define NTOK 16384
#define DIM  4096
#define NEXP 64
#define BM   64
#define BK   32
#define LDST 68   // padded LDS leading stride (floats): 68*4=272B, 16B-aligned, banks spread
#define NCHUNK (DIM / BK)

__device__ __forceinline__ bool better(float v, int i, float wv, int wi) {
  // strict "is (v,i) ranked above (wv,wi)" with lax.top_k tie-break (lower index wins)
  return (v > wv) || (v == wv && i < wi);
}

__global__ __launch_bounds__(256, 1) void moe_router(
    const float* __restrict__ tokens,
    const float* __restrict__ W,
    float* __restrict__ out)
{
  __shared__ float As[2][BK * LDST];
  __shared__ float Bs[2][BK * LDST];

  const int tid = threadIdx.x;
  const int tx = tid & 15;     // expert-tile column group (4 experts each)
  const int ty = tid >> 4;     // token-tile row group (4 tokens each)
  const int t0 = blockIdx.x * BM;

  // staging-load mapping: 8 lanes per row, each lane one float4 (coalesced 128B/row)
  const int l_kq  = tid & 7;   // k quad index: k = l_kq*4
  const int l_row = tid >> 3;  // 0..31 (second pass +32)

  const float* Abase = tokens + (size_t)t0 * DIM;

  float acc[4][4];
  #pragma unroll
  for (int m = 0; m < 4; ++m)
    #pragma unroll
    for (int n = 0; n < 4; ++n) acc[m][n] = 0.f;

  float4 apf[2], bpf[2];

  // ---- prologue: load + stage chunk 0 ----
  #pragma unroll
  for (int i = 0; i < 2; ++i) {
    const int row = l_row + i * 32;
    apf[i] = *(const float4*)(Abase + (size_t)row * DIM + (l_kq << 2));
    bpf[i] = *(const float4*)(W     + (size_t)row * DIM + (l_kq << 2));
  }
  #pragma unroll
  for (int i = 0; i < 2; ++i) {
    const int row = l_row + i * 32;
    const float* av = (const float*)&apf[i];
    const float* bv = (const float*)&bpf[i];
    #pragma unroll
    for (int j = 0; j < 4; ++j) {
      As[0][(l_kq * 4 + j) * LDST + row] = av[j];   // k-major (transposed) store
      Bs[0][(l_kq * 4 + j) * LDST + row] = bv[j];
    }
  }
  __syncthreads();

  // ---- K loop: double-buffered, one barrier per chunk ----
  for (int c = 0; c < NCHUNK; ++c) {
    const int cur = c & 1;
    const bool has_next = (c + 1 < NCHUNK);
    if (has_next) {
      const int k0 = (c + 1) * BK;
      #pragma unroll
      for (int i = 0; i < 2; ++i) {
        const int row = l_row + i * 32;
        apf[i] = *(const float4*)(Abase + (size_t)row * DIM + k0 + (l_kq << 2));
        bpf[i] = *(const float4*)(W     + (size_t)row * DIM + k0 + (l_kq << 2));
      }
    }
    const float* __restrict__ Ab = As[cur];
    const float* __restrict__ Bb = Bs[cur];
    #pragma unroll
    for (int k = 0; k < BK; ++k) {
      const float4 av4 = *(const float4*)(Ab + k * LDST + (ty << 2));
      const float4 bv4 = *(const float4*)(Bb + k * LDST + (tx << 2));
      const float a[4] = {av4.x, av4.y, av4.z, av4.w};
      const float b[4] = {bv4.x, bv4.y, bv4.z, bv4.w};
      #pragma unroll
      for (int m = 0; m < 4; ++m)
        #pragma unroll
        for (int n = 0; n < 4; ++n)
          acc[m][n] = fmaf(a[m], b[n], acc[m][n]);
    }
    if (has_next) {
      const int nxt = cur ^ 1;
      #pragma unroll
      for (int i = 0; i < 2; ++i) {
        const int row = l_row + i * 32;
        const float* av = (const float*)&apf[i];
        const float* bv = (const float*)&bpf[i];
        #pragma unroll
        for (int j = 0; j < 4; ++j) {
          As[nxt][(l_kq * 4 + j) * LDST + row] = av[j];
          Bs[nxt][(l_kq * 4 + j) * LDST + row] = bv[j];
        }
      }
    }
    __syncthreads();
  }

  // ---- epilogue: per token row, top-2 of logits + softmax scores ----
  #pragma unroll
  for (int m = 0; m < 4; ++m) {
    float t1v = acc[m][0]; int t1i = tx * 4;
    float t2v = -INFINITY; int t2i = NEXP;
    #pragma unroll
    for (int n = 1; n < 4; ++n) {
      const float v = acc[m][n]; const int e = tx * 4 + n;
      if (better(v, e, t1v, t1i)) { t2v = t1v; t2i = t1i; t1v = v; t1i = e; }
      else if (better(v, e, t2v, t2i)) { t2v = v; t2i = e; }
    }
    // butterfly merge of sorted top-2 pairs across the 16 lanes sharing this row
    #pragma unroll
    for (int mask = 1; mask < 16; mask <<= 1) {
      const float o1v = __shfl_xor(t1v, mask, 16);
      const int   o1i = __shfl_xor(t1i, mask, 16);
      const float o2v = __shfl_xor(t2v, mask, 16);
      const int   o2i = __shfl_xor(t2i, mask, 16);
      if (better(o1v, o1i, t1v, t1i)) {
        if (better(t1v, t1i, o2v, o2i)) { t2v = t1v; t2i = t1i; }
        else                            { t2v = o2v; t2i = o2i; }
        t1v = o1v; t1i = o1i;
      } else {
        if (better(o1v, o1i, t2v, t2i)) { t2v = o1v; t2i = o1i; }
      }
    }
    // softmax denominator over all 64 experts (max = t1v by construction)
    const float M = t1v;
    float s = 0.f;
    #pragma unroll
    for (int n = 0; n < 4; ++n) s += expf(acc[m][n] - M);
    #pragma unroll
    for (int mask = 1; mask < 16; mask <<= 1) s += __shfl_xor(s, mask, 16);

    if (tx == 0) {
      const int t = t0 + ty * 4 + m;
      const float inv = 1.0f / s;
      out[t * 2 + 0] = inv;                       // exp(0)/den
      out[t * 2 + 1] = expf(t2v - M) * inv;
      out[NTOK * 2 + t * 2 + 0] = (float)t1i;     // indices as float
      out[NTOK * 2 + t * 2 + 1] = (float)t2i;
    }
  }
}

extern "C" void kernel_launch(void* const* d_in, const int* in_sizes, int n_in,
                              void* d_out, int out_size, void* d_ws, size_t ws_size,
                              hipStream_t stream) {
  const float* tokens = (const float*)d_in[0];
  const float* W      = (const float*)d_in[1];
  float* out          = (float*)d_out;
  moe_router<<<NTOK / BM, 256, 0, stream>>>(tokens, W, out);
}